// Round 1
// baseline (530.117 us; speedup 1.0000x reference)
//
#include <hip/hip_runtime.h>

// Problem: B=64, T=1024, D=512, H=512, O=128, HALF=256, ALPHA_M=0.8
// Pipeline: gemm1 (x -> din1/din2 bf16) -> chunked scan (-> mems bf16) -> gemm2 (+sigmoid -> out fp32)

#define B_    64
#define T_    1024
#define D_    512
#define H_    512
#define O_    128
#define HALF_ 256

typedef __attribute__((ext_vector_type(4))) float        f32x4;
typedef __attribute__((ext_vector_type(8))) short        s16x8;
typedef __attribute__((ext_vector_type(4))) unsigned int u32x4;

__device__ __forceinline__ unsigned short f2bf(float f) {
    unsigned u = __float_as_uint(f);
    return (unsigned short)((u + 0x7fffu + ((u >> 16) & 1u)) >> 16);  // RNE
}
__device__ __forceinline__ unsigned packbf(float a, float b) {
    return (unsigned)f2bf(a) | ((unsigned)f2bf(b) << 16);
}
__device__ __forceinline__ float bflo(unsigned u) { return __uint_as_float(u << 16); }
__device__ __forceinline__ float bfhi(unsigned u) { return __uint_as_float(u & 0xffff0000u); }

// ---------------- GEMM1: din{1,2}[b,t,h] = x[b,t,koff:koff+256] . w[h,:]  (bf16 MFMA) ----
// Tile 128x128, BK=64, LDS stride 72 (pad +8 keeps 16B align, 2-way conflicts only)
__global__ __launch_bounds__(256, 2) void gemm1_kernel(
    const float* __restrict__ x, const float* __restrict__ w1,
    const float* __restrict__ w2, unsigned short* __restrict__ din1,
    unsigned short* __restrict__ din2)
{
    __shared__ short As[128 * 72];
    __shared__ short Bs[128 * 72];

    const int nt = blockIdx.x;   // 0..3   (N tile; fastest for x L2 reuse)
    const int mt = blockIdx.y;   // 0..511
    const int br = blockIdx.z;   // branch
    const float* w = br ? w2 : w1;
    unsigned short* dout = br ? din2 : din1;
    const int koff = br * HALF_;

    const int tid  = threadIdx.x;
    const int srow = tid >> 1;          // 0..127 staging row
    const int skh  = (tid & 1) << 5;    // 0 / 32 k-half

    const int lane = tid & 63;
    const int wm = ((tid >> 6) & 1) << 6;
    const int wn = ((tid >> 6) >> 1) << 6;
    const int ln = lane & 15;
    const int qd = lane >> 4;

    f32x4 acc[4][4] = {};

    const float* aptr = x + (size_t)(mt * 128 + srow) * D_ + koff + skh;
    const float* bptr = w + (size_t)(nt * 128 + srow) * HALF_ + skh;
    short* asw = &As[srow * 72 + skh];
    short* bsw = &Bs[srow * 72 + skh];

    for (int kt = 0; kt < HALF_; kt += 64) {
        #pragma unroll
        for (int i = 0; i < 4; ++i) {
            f32x4 a0 = *(const f32x4*)(aptr + kt + i * 8);
            f32x4 a1 = *(const f32x4*)(aptr + kt + i * 8 + 4);
            u32x4 pa;
            pa.x = packbf(a0.x, a0.y); pa.y = packbf(a0.z, a0.w);
            pa.z = packbf(a1.x, a1.y); pa.w = packbf(a1.z, a1.w);
            *(u32x4*)(asw + i * 8) = pa;

            f32x4 b0 = *(const f32x4*)(bptr + kt + i * 8);
            f32x4 b1 = *(const f32x4*)(bptr + kt + i * 8 + 4);
            u32x4 pb;
            pb.x = packbf(b0.x, b0.y); pb.y = packbf(b0.z, b0.w);
            pb.z = packbf(b1.x, b1.y); pb.w = packbf(b1.z, b1.w);
            *(u32x4*)(bsw + i * 8) = pb;
        }
        __syncthreads();
        #pragma unroll
        for (int ks = 0; ks < 64; ks += 32) {
            s16x8 af[4], bfv[4];
            #pragma unroll
            for (int i = 0; i < 4; ++i)
                af[i] = *(const s16x8*)&As[(wm + i * 16 + ln) * 72 + ks + qd * 8];
            #pragma unroll
            for (int j = 0; j < 4; ++j)
                bfv[j] = *(const s16x8*)&Bs[(wn + j * 16 + ln) * 72 + ks + qd * 8];
            #pragma unroll
            for (int i = 0; i < 4; ++i)
                #pragma unroll
                for (int j = 0; j < 4; ++j)
                    acc[i][j] = __builtin_amdgcn_mfma_f32_16x16x32_bf16(
                        af[i], bfv[j], acc[i][j], 0, 0, 0);
        }
        __syncthreads();
    }

    // epilogue: D row = wm + i*16 + qd*4 + r, col = wn + j*16 + ln
    unsigned short* orow = dout + (size_t)(mt * 128 + wm + qd * 4) * H_ + nt * 128 + wn + ln;
    #pragma unroll
    for (int i = 0; i < 4; ++i)
        #pragma unroll
        for (int j = 0; j < 4; ++j)
            #pragma unroll
            for (int r = 0; r < 4; ++r)
                orow[(size_t)(i * 16 + r) * H_ + j * 16] = f2bf(acc[i][j][r]);
}

// ---------------- Chunked scan: mems[b,t,h] (bf16x2 packed) ------------------------------
// Chunk len 128, warm-up 192 steps (a1=sig(3.0): a1^192 ~ 9e-5 -> truncation error ~1e-4)
#define CLEN 128
#define WARM 192

__global__ __launch_bounds__(256) void scan_kernel(
    const unsigned short* __restrict__ din1, const unsigned short* __restrict__ din2,
    const float* __restrict__ b1, const float* __restrict__ tau1,
    const float* __restrict__ b2, const float* __restrict__ tau2,
    unsigned int* __restrict__ mems)   // packed 2x bf16 per uint
{
    const int h2 = threadIdx.x;        // 0..255 (pair of h)
    const int c  = blockIdx.x & 7;     // chunk
    const int b  = blockIdx.x >> 3;    // batch
    const int h0 = h2 << 1;

    const float a1a = 1.f / (1.f + __expf(-tau1[h0]));
    const float a1b = 1.f / (1.f + __expf(-tau1[h0 + 1]));
    const float a2a = 1.f / (1.f + __expf(-tau2[h0]));
    const float a2b = 1.f / (1.f + __expf(-tau2[h0 + 1]));
    const float o1a = 1.f - a1a, o1b = 1.f - a1b;
    const float o2a = 1.f - a2a, o2b = 1.f - a2b;
    const float bb1a = b1[h0], bb1b = b1[h0 + 1];
    const float bb2a = b2[h0], bb2b = b2[h0 + 1];
    const float am = 0.8f, om = 1.0f - am;

    const unsigned int* p1 = (const unsigned int*)din1;
    const unsigned int* p2 = (const unsigned int*)din2;
    const size_t base = (size_t)b * T_ * (H_ / 2) + h2;

    float d1a = 0.f, d1b = 0.f, d2a = 0.f, d2b = 0.f, ma = 0.f, mb = 0.f;
    const int t0 = c * CLEN;
    int t = (t0 >= WARM) ? (t0 - WARM) : 0;

    for (; t < t0; ++t) {
        unsigned u1 = p1[base + (size_t)t * (H_ / 2)];
        unsigned u2 = p2[base + (size_t)t * (H_ / 2)];
        float i1a = bflo(u1) + bb1a, i1b = bfhi(u1) + bb1b;
        float i2a = bflo(u2) + bb2a, i2b = bfhi(u2) + bb2b;
        d1a = a1a * d1a + o1a * i1a;  d1b = a1b * d1b + o1b * i1b;
        d2a = a2a * d2a + o2a * i2a;  d2b = a2b * d2b + o2b * i2b;
        ma = am * ma + om * (d1a + d2a);
        mb = am * mb + om * (d1b + d2b);
    }
    for (; t < t0 + CLEN; ++t) {
        unsigned u1 = p1[base + (size_t)t * (H_ / 2)];
        unsigned u2 = p2[base + (size_t)t * (H_ / 2)];
        float i1a = bflo(u1) + bb1a, i1b = bfhi(u1) + bb1b;
        float i2a = bflo(u2) + bb2a, i2b = bfhi(u2) + bb2b;
        d1a = a1a * d1a + o1a * i1a;  d1b = a1b * d1b + o1b * i1b;
        d2a = a2a * d2a + o2a * i2a;  d2b = a2b * d2b + o2b * i2b;
        ma = am * ma + om * (d1a + d2a);
        mb = am * mb + om * (d1b + d2b);
        mems[base + (size_t)t * (H_ / 2)] = packbf(ma, mb);
    }
}

// ---------------- GEMM2: out[b,t,o] = sigmoid(mems[b,t,:] . wo[o,:] + bo[o]) -------------
__global__ __launch_bounds__(256, 2) void gemm2_kernel(
    const unsigned short* __restrict__ mems, const float* __restrict__ wo,
    const float* __restrict__ bo, float* __restrict__ out)
{
    __shared__ short As[128 * 72];
    __shared__ short Bs[128 * 72];

    const int mt = blockIdx.x;          // 0..511
    const int tid  = threadIdx.x;
    const int srow = tid >> 1;
    const int skh  = (tid & 1) << 5;

    const int lane = tid & 63;
    const int wm = ((tid >> 6) & 1) << 6;
    const int wn = ((tid >> 6) >> 1) << 6;
    const int ln = lane & 15;
    const int qd = lane >> 4;

    f32x4 acc[4][4] = {};

    const unsigned short* aptr = mems + (size_t)(mt * 128 + srow) * H_ + skh;
    const float* bptr = wo + (size_t)srow * H_ + skh;
    short* asw = &As[srow * 72 + skh];
    short* bsw = &Bs[srow * 72 + skh];

    for (int kt = 0; kt < H_; kt += 64) {
        #pragma unroll
        for (int i = 0; i < 4; ++i)
            *(u32x4*)(asw + i * 8) = *(const u32x4*)(aptr + kt + i * 8);
        #pragma unroll
        for (int i = 0; i < 4; ++i) {
            f32x4 b0 = *(const f32x4*)(bptr + kt + i * 8);
            f32x4 b1 = *(const f32x4*)(bptr + kt + i * 8 + 4);
            u32x4 pb;
            pb.x = packbf(b0.x, b0.y); pb.y = packbf(b0.z, b0.w);
            pb.z = packbf(b1.x, b1.y); pb.w = packbf(b1.z, b1.w);
            *(u32x4*)(bsw + i * 8) = pb;
        }
        __syncthreads();
        #pragma unroll
        for (int ks = 0; ks < 64; ks += 32) {
            s16x8 af[4], bfv[4];
            #pragma unroll
            for (int i = 0; i < 4; ++i)
                af[i] = *(const s16x8*)&As[(wm + i * 16 + ln) * 72 + ks + qd * 8];
            #pragma unroll
            for (int j = 0; j < 4; ++j)
                bfv[j] = *(const s16x8*)&Bs[(wn + j * 16 + ln) * 72 + ks + qd * 8];
            #pragma unroll
            for (int i = 0; i < 4; ++i)
                #pragma unroll
                for (int j = 0; j < 4; ++j)
                    acc[i][j] = __builtin_amdgcn_mfma_f32_16x16x32_bf16(
                        af[i], bfv[j], acc[i][j], 0, 0, 0);
        }
        __syncthreads();
    }

    float bov[4];
    #pragma unroll
    for (int j = 0; j < 4; ++j) bov[j] = bo[wn + j * 16 + ln];

    float* orow = out + (size_t)(mt * 128 + wm + qd * 4) * O_ + wn + ln;
    #pragma unroll
    for (int i = 0; i < 4; ++i)
        #pragma unroll
        for (int j = 0; j < 4; ++j)
            #pragma unroll
            for (int r = 0; r < 4; ++r) {
                float v = acc[i][j][r] + bov[j];
                orow[(size_t)(i * 16 + r) * O_ + j * 16] = 1.f / (1.f + __expf(-v));
            }
}

extern "C" void kernel_launch(void* const* d_in, const int* in_sizes, int n_in,
                              void* d_out, int out_size, void* d_ws, size_t ws_size,
                              hipStream_t stream) {
    const float* x    = (const float*)d_in[0];
    const float* w1   = (const float*)d_in[1];
    const float* b1   = (const float*)d_in[2];
    const float* tau1 = (const float*)d_in[3];
    const float* w2   = (const float*)d_in[4];
    const float* b2   = (const float*)d_in[5];
    const float* tau2 = (const float*)d_in[6];
    const float* wo   = (const float*)d_in[7];
    const float* bo   = (const float*)d_in[8];
    float* out = (float*)d_out;

    // ws: din1 (64MB), din2 (64MB), mems (64MB) -- all bf16 [B,T,H]; need 192 MiB total
    unsigned short* din1 = (unsigned short*)d_ws;
    unsigned short* din2 = din1 + (size_t)B_ * T_ * H_;
    unsigned short* mems = din2 + (size_t)B_ * T_ * H_;

    gemm1_kernel<<<dim3(4, 512, 2), 256, 0, stream>>>(x, w1, w2, din1, din2);
    scan_kernel<<<dim3(B_ * 8), 256, 0, stream>>>(din1, din2, b1, tau1, b2, tau2,
                                                  (unsigned int*)mems);
    gemm2_kernel<<<dim3(512), 256, 0, stream>>>(mems, wo, bo, out);
}

// Round 2
// 366.227 us; speedup vs baseline: 1.4475x; 1.4475x over previous
//
#include <hip/hip_runtime.h>

// B=64 T=1024 D=512 H=512 O=128 HALF=256 ALPHA_M=0.8
// Pipeline: cast(x->bf16) -> gemm1(async-LDS MFMA -> din1,din2 bf16)
//           -> scanA (local chunk scans, in-place mems over din1, end-states)
//           -> scanB (combine chunk states, closed-form decay)
//           -> scanC (parallel fix-up of mems)
//           -> gemm2 (MFMA + bias + sigmoid -> out fp32)

#define B_    64
#define T_    1024
#define D_    512
#define H_    512
#define O_    128
#define HALF_ 256
#define CLEN  32
#define NC    32    // T_/CLEN

typedef __attribute__((ext_vector_type(4))) float        f32x4;
typedef __attribute__((ext_vector_type(2))) float        f32x2;
typedef __attribute__((ext_vector_type(8))) short        s16x8;
typedef __attribute__((ext_vector_type(4))) unsigned int u32x4;

__device__ __forceinline__ unsigned short f2bf(float f) {
    unsigned u = __float_as_uint(f);
    return (unsigned short)((u + 0x7fffu + ((u >> 16) & 1u)) >> 16);  // RNE
}
__device__ __forceinline__ unsigned packbf(float a, float b) {
    return (unsigned)f2bf(a) | ((unsigned)f2bf(b) << 16);
}
__device__ __forceinline__ float bflo(unsigned u) { return __uint_as_float(u << 16); }
__device__ __forceinline__ float bfhi(unsigned u) { return __uint_as_float(u & 0xffff0000u); }
__device__ __forceinline__ float sigf(float x) { return 1.f / (1.f + __expf(-x)); }
__device__ __forceinline__ float pw32(float a) {  // a^32
    float t = a * a; t *= t; t *= t; t *= t; t *= t; return t;
}

typedef const __attribute__((address_space(1))) unsigned int gu32;
typedef __attribute__((address_space(3))) unsigned int      lu32;
__device__ __forceinline__ void gl_lds16(const void* g, void* l) {
    __builtin_amdgcn_global_load_lds((gu32*)g, (lu32*)l, 16, 0, 0);
}

// ---------------- cast: x fp32 -> xb bf16 (packed) ---------------------------------------
__global__ __launch_bounds__(256) void cast_kernel(const float* __restrict__ x,
                                                   unsigned int* __restrict__ xb) {
    size_t i = ((size_t)blockIdx.x * 256 + threadIdx.x) * 8;
    f32x4 a = *(const f32x4*)(x + i);
    f32x4 b = *(const f32x4*)(x + i + 4);
    u32x4 p;
    p.x = packbf(a.x, a.y); p.y = packbf(a.z, a.w);
    p.z = packbf(b.x, b.y); p.w = packbf(b.z, b.w);
    *(u32x4*)(xb + i / 2) = p;
}

// ---------------- GEMM1: din{1,2}[m,h] = xb[m, koff:+256] . w[h,:]  ----------------------
// A via global_load_lds (bf16, swizzled), B via VALU pack (fp32 weights, L2-resident)
__global__ __launch_bounds__(256, 2) void gemm1_kernel(
    const unsigned short* __restrict__ xb, const float* __restrict__ w1,
    const float* __restrict__ w2, unsigned short* __restrict__ din1,
    unsigned short* __restrict__ din2)
{
    __shared__ short As[128 * 64];
    __shared__ short Bs[128 * 64];

    const int nt = blockIdx.x, mt = blockIdx.y, br = blockIdx.z;
    const float* w = br ? w2 : w1;
    unsigned short* dout = br ? din2 : din1;
    const int koff = br * HALF_;

    const int tid = threadIdx.x, l = tid & 63, wv = tid >> 6;
    const int ln = l & 15, qd = l >> 4;
    const int wm = (wv & 1) << 6, wn = (wv >> 1) << 6;

    f32x4 acc[4][4] = {};

    const unsigned short* abase = xb + (size_t)(mt * 128) * D_ + koff;
    const float* wbase = w + (size_t)(nt * 128) * HALF_;

    for (int kt = 0; kt < HALF_; kt += 64) {
        // A tile: 16 chunks of 1024B; wave wv stages chunks wv*4..+3 (lane gets 16B)
        #pragma unroll
        for (int i = 0; i < 4; ++i) {
            int ch = wv * 4 + i;
            int r  = ch * 8 + (l >> 3);
            int kbl = (l & 7) ^ (r & 7);                 // XOR swizzle (conflict-free reads)
            gl_lds16(abase + (size_t)r * D_ + kt + kbl * 8, &As[ch * 512 + l * 8]);
        }
        // B tile: VALU pack, 1024 groups of 8 shorts
        #pragma unroll
        for (int i = 0; i < 4; ++i) {
            int gi = i * 256 + tid;
            int r = gi >> 3, kbp = gi & 7, kbl = kbp ^ (r & 7);
            const float* src = wbase + (size_t)r * HALF_ + kt + kbl * 8;
            f32x4 b0 = *(const f32x4*)src;
            f32x4 b1v = *(const f32x4*)(src + 4);
            u32x4 pb;
            pb.x = packbf(b0.x, b0.y); pb.y = packbf(b0.z, b0.w);
            pb.z = packbf(b1v.x, b1v.y); pb.w = packbf(b1v.z, b1v.w);
            *(u32x4*)&Bs[r * 64 + kbp * 8] = pb;
        }
        __syncthreads();
        #pragma unroll
        for (int ks = 0; ks < 64; ks += 32) {
            s16x8 af[4], bfv[4];
            #pragma unroll
            for (int i = 0; i < 4; ++i) {
                int r = wm + i * 16 + ln;
                int kbp = ((ks >> 3) + qd) ^ (r & 7);
                af[i] = *(const s16x8*)&As[r * 64 + kbp * 8];
            }
            #pragma unroll
            for (int j = 0; j < 4; ++j) {
                int r = wn + j * 16 + ln;
                int kbp = ((ks >> 3) + qd) ^ (r & 7);
                bfv[j] = *(const s16x8*)&Bs[r * 64 + kbp * 8];
            }
            #pragma unroll
            for (int i = 0; i < 4; ++i)
                #pragma unroll
                for (int j = 0; j < 4; ++j)
                    acc[i][j] = __builtin_amdgcn_mfma_f32_16x16x32_bf16(
                        af[i], bfv[j], acc[i][j], 0, 0, 0);
        }
        __syncthreads();
    }

    unsigned short* orow = dout + (size_t)(mt * 128 + wm + qd * 4) * H_ + nt * 128 + wn + ln;
    #pragma unroll
    for (int i = 0; i < 4; ++i)
        #pragma unroll
        for (int j = 0; j < 4; ++j)
            #pragma unroll
            for (int r = 0; r < 4; ++r)
                orow[(size_t)(i * 16 + r) * H_ + j * 16] = f2bf(acc[i][j][r]);
}

// ---------------- scanA: local chunk scans (zero init), in-place mems, end-states --------
__global__ __launch_bounds__(256) void scanA_kernel(
    unsigned int* __restrict__ m1,        // din1: read input, write local mems in place
    const unsigned int* __restrict__ p2,  // din2
    const float* __restrict__ b1, const float* __restrict__ tau1,
    const float* __restrict__ b2, const float* __restrict__ tau2,
    float* __restrict__ Sd1, float* __restrict__ Sd2, float* __restrict__ Sm)
{
    const int h2 = threadIdx.x;
    const int c = blockIdx.x & (NC - 1);
    const int b = blockIdx.x >> 5;
    const int h0 = h2 << 1;

    const float a1a = sigf(tau1[h0]), a1b = sigf(tau1[h0 + 1]);
    const float a2a = sigf(tau2[h0]), a2b = sigf(tau2[h0 + 1]);
    const float o1a = 1.f - a1a, o1b = 1.f - a1b;
    const float o2a = 1.f - a2a, o2b = 1.f - a2b;
    const float bb1a = b1[h0], bb1b = b1[h0 + 1];
    const float bb2a = b2[h0], bb2b = b2[h0 + 1];

    const size_t base = ((size_t)b * T_ + c * CLEN) * (H_ / 2) + h2;
    float d1a = 0.f, d1b = 0.f, d2a = 0.f, d2b = 0.f, ma = 0.f, mb = 0.f;

    #pragma unroll 8
    for (int k = 0; k < CLEN; ++k) {
        unsigned u1 = m1[base + (size_t)k * (H_ / 2)];
        unsigned u2 = p2[base + (size_t)k * (H_ / 2)];
        float i1a = bflo(u1) + bb1a, i1b = bfhi(u1) + bb1b;
        float i2a = bflo(u2) + bb2a, i2b = bfhi(u2) + bb2b;
        d1a = a1a * d1a + o1a * i1a;  d1b = a1b * d1b + o1b * i1b;
        d2a = a2a * d2a + o2a * i2a;  d2b = a2b * d2b + o2b * i2b;
        ma = 0.8f * ma + 0.2f * (d1a + d2a);
        mb = 0.8f * mb + 0.2f * (d1b + d2b);
        m1[base + (size_t)k * (H_ / 2)] = packbf(ma, mb);
    }

    const size_t si = ((size_t)c * B_ + b) * H_ + h0;
    f32x2 v;
    v.x = d1a; v.y = d1b; *(f32x2*)&Sd1[si] = v;
    v.x = d2a; v.y = d2b; *(f32x2*)&Sd2[si] = v;
    v.x = ma;  v.y = mb;  *(f32x2*)&Sm[si]  = v;
}

// ---------------- scanB: sequential chunk-state combine (tiny) ---------------------------
__global__ __launch_bounds__(128) void scanB_kernel(
    const float* __restrict__ Sd1, const float* __restrict__ Sd2,
    const float* __restrict__ Sm,
    const float* __restrict__ tau1, const float* __restrict__ tau2,
    float* __restrict__ D1, float* __restrict__ D2, float* __restrict__ DM)
{
    const int g = blockIdx.x * 128 + threadIdx.x;  // 0..16383
    const int h2 = g & 255, b = g >> 8, h0 = h2 << 1;

    const float a1a = sigf(tau1[h0]), a1b = sigf(tau1[h0 + 1]);
    const float a2a = sigf(tau2[h0]), a2b = sigf(tau2[h0 + 1]);
    const float amL = pw32(0.8f);
    const float a1La = pw32(a1a), a1Lb = pw32(a1b);
    const float a2La = pw32(a2a), a2Lb = pw32(a2b);

    float dn;
    dn = 0.8f - a1a; if (fabsf(dn) < 1e-6f) dn = (dn < 0.f ? -1e-6f : 1e-6f);
    const float c1a = 0.2f * a1a / dn;
    dn = 0.8f - a1b; if (fabsf(dn) < 1e-6f) dn = (dn < 0.f ? -1e-6f : 1e-6f);
    const float c1b = 0.2f * a1b / dn;
    dn = 0.8f - a2a; if (fabsf(dn) < 1e-6f) dn = (dn < 0.f ? -1e-6f : 1e-6f);
    const float c2a = 0.2f * a2a / dn;
    dn = 0.8f - a2b; if (fabsf(dn) < 1e-6f) dn = (dn < 0.f ? -1e-6f : 1e-6f);
    const float c2b = 0.2f * a2b / dn;

    const float g1La = c1a * (amL - a1La), g1Lb = c1b * (amL - a1Lb);
    const float g2La = c2a * (amL - a2La), g2Lb = c2b * (amL - a2Lb);

    float D1a = 0.f, D1b = 0.f, D2a = 0.f, D2b = 0.f, Ma = 0.f, Mb = 0.f;
    for (int c = 0; c < NC; ++c) {
        const size_t si = ((size_t)c * B_ + b) * H_ + h0;
        if (c) {
            f32x2 v;
            v.x = D1a; v.y = D1b; *(f32x2*)&D1[si] = v;
            v.x = D2a; v.y = D2b; *(f32x2*)&D2[si] = v;
            v.x = Ma;  v.y = Mb;  *(f32x2*)&DM[si] = v;
        }
        f32x2 s1 = *(const f32x2*)&Sd1[si];
        f32x2 s2 = *(const f32x2*)&Sd2[si];
        f32x2 sm = *(const f32x2*)&Sm[si];
        float nMa = amL * Ma + D1a * g1La + D2a * g2La + sm.x;
        float nMb = amL * Mb + D1b * g1Lb + D2b * g2Lb + sm.y;
        D1a = a1La * D1a + s1.x;  D1b = a1Lb * D1b + s1.y;
        D2a = a2La * D2a + s2.x;  D2b = a2Lb * D2b + s2.y;
        Ma = nMa;  Mb = nMb;
    }
}

// ---------------- scanC: parallel fix-up of mems ----------------------------------------
__global__ __launch_bounds__(256) void scanC_kernel(
    unsigned int* __restrict__ mems,
    const float* __restrict__ tau1, const float* __restrict__ tau2,
    const float* __restrict__ D1, const float* __restrict__ D2,
    const float* __restrict__ DM)
{
    const int h2 = threadIdx.x;
    const int c = blockIdx.x % (NC - 1) + 1;   // 1..31 (chunk 0 needs no fix-up)
    const int b = blockIdx.x / (NC - 1);
    const int h0 = h2 << 1;

    const size_t si = ((size_t)c * B_ + b) * H_ + h0;
    f32x2 d1 = *(const f32x2*)&D1[si];
    f32x2 d2 = *(const f32x2*)&D2[si];
    f32x2 mm = *(const f32x2*)&DM[si];

    const float a1a = sigf(tau1[h0]), a1b = sigf(tau1[h0 + 1]);
    const float a2a = sigf(tau2[h0]), a2b = sigf(tau2[h0 + 1]);
    float dn;
    dn = 0.8f - a1a; if (fabsf(dn) < 1e-6f) dn = (dn < 0.f ? -1e-6f : 1e-6f);
    const float c1a = 0.2f * a1a / dn;
    dn = 0.8f - a1b; if (fabsf(dn) < 1e-6f) dn = (dn < 0.f ? -1e-6f : 1e-6f);
    const float c1b = 0.2f * a1b / dn;
    dn = 0.8f - a2a; if (fabsf(dn) < 1e-6f) dn = (dn < 0.f ? -1e-6f : 1e-6f);
    const float c2a = 0.2f * a2a / dn;
    dn = 0.8f - a2b; if (fabsf(dn) < 1e-6f) dn = (dn < 0.f ? -1e-6f : 1e-6f);
    const float c2b = 0.2f * a2b / dn;

    float pm = 1.f, p1a = 1.f, p1b = 1.f, p2a = 1.f, p2b = 1.f;
    const size_t base = ((size_t)b * T_ + c * CLEN) * (H_ / 2) + h2;

    #pragma unroll 8
    for (int k = 0; k < CLEN; ++k) {
        pm *= 0.8f; p1a *= a1a; p1b *= a1b; p2a *= a2a; p2b *= a2b;
        float g1a = c1a * (pm - p1a), g2a = c2a * (pm - p2a);
        float g1b = c1b * (pm - p1b), g2b = c2b * (pm - p2b);
        unsigned u = mems[base + (size_t)k * (H_ / 2)];
        float va = bflo(u) + d1.x * g1a + d2.x * g2a + mm.x * pm;
        float vb = bfhi(u) + d1.y * g1b + d2.y * g2b + mm.y * pm;
        mems[base + (size_t)k * (H_ / 2)] = packbf(va, vb);
    }
}

// ---------------- GEMM2: out = sigmoid(mems . wo^T + bo) --------------------------------
__global__ __launch_bounds__(256, 2) void gemm2_kernel(
    const unsigned short* __restrict__ mems, const float* __restrict__ wo,
    const float* __restrict__ bo, float* __restrict__ out)
{
    __shared__ short As[128 * 64];
    __shared__ short Bs[128 * 64];

    const int mt = blockIdx.x;
    const int tid = threadIdx.x, l = tid & 63, wv = tid >> 6;
    const int ln = l & 15, qd = l >> 4;
    const int wm = (wv & 1) << 6, wn = (wv >> 1) << 6;

    f32x4 acc[4][4] = {};
    const unsigned short* abase = mems + (size_t)(mt * 128) * H_;

    for (int kt = 0; kt < H_; kt += 64) {
        #pragma unroll
        for (int i = 0; i < 4; ++i) {
            int ch = wv * 4 + i;
            int r  = ch * 8 + (l >> 3);
            int kbl = (l & 7) ^ (r & 7);
            gl_lds16(abase + (size_t)r * H_ + kt + kbl * 8, &As[ch * 512 + l * 8]);
        }
        #pragma unroll
        for (int i = 0; i < 4; ++i) {
            int gi = i * 256 + tid;
            int r = gi >> 3, kbp = gi & 7, kbl = kbp ^ (r & 7);
            const float* src = wo + (size_t)r * H_ + kt + kbl * 8;
            f32x4 b0 = *(const f32x4*)src;
            f32x4 b1v = *(const f32x4*)(src + 4);
            u32x4 pb;
            pb.x = packbf(b0.x, b0.y); pb.y = packbf(b0.z, b0.w);
            pb.z = packbf(b1v.x, b1v.y); pb.w = packbf(b1v.z, b1v.w);
            *(u32x4*)&Bs[r * 64 + kbp * 8] = pb;
        }
        __syncthreads();
        #pragma unroll
        for (int ks = 0; ks < 64; ks += 32) {
            s16x8 af[4], bfv[4];
            #pragma unroll
            for (int i = 0; i < 4; ++i) {
                int r = wm + i * 16 + ln;
                int kbp = ((ks >> 3) + qd) ^ (r & 7);
                af[i] = *(const s16x8*)&As[r * 64 + kbp * 8];
            }
            #pragma unroll
            for (int j = 0; j < 4; ++j) {
                int r = wn + j * 16 + ln;
                int kbp = ((ks >> 3) + qd) ^ (r & 7);
                bfv[j] = *(const s16x8*)&Bs[r * 64 + kbp * 8];
            }
            #pragma unroll
            for (int i = 0; i < 4; ++i)
                #pragma unroll
                for (int j = 0; j < 4; ++j)
                    acc[i][j] = __builtin_amdgcn_mfma_f32_16x16x32_bf16(
                        af[i], bfv[j], acc[i][j], 0, 0, 0);
        }
        __syncthreads();
    }

    float bov[4];
    #pragma unroll
    for (int j = 0; j < 4; ++j) bov[j] = bo[wn + j * 16 + ln];

    float* orow = out + (size_t)(mt * 128 + wm + qd * 4) * O_ + wn + ln;
    #pragma unroll
    for (int i = 0; i < 4; ++i)
        #pragma unroll
        for (int j = 0; j < 4; ++j)
            #pragma unroll
            for (int r = 0; r < 4; ++r) {
                float v = acc[i][j][r] + bov[j];
                orow[(size_t)(i * 16 + r) * O_ + j * 16] = 1.f / (1.f + __expf(-v));
            }
}

extern "C" void kernel_launch(void* const* d_in, const int* in_sizes, int n_in,
                              void* d_out, int out_size, void* d_ws, size_t ws_size,
                              hipStream_t stream) {
    const float* x    = (const float*)d_in[0];
    const float* w1   = (const float*)d_in[1];
    const float* b1   = (const float*)d_in[2];
    const float* tau1 = (const float*)d_in[3];
    const float* w2   = (const float*)d_in[4];
    const float* b2   = (const float*)d_in[5];
    const float* tau2 = (const float*)d_in[6];
    const float* wo   = (const float*)d_in[7];
    const float* bo   = (const float*)d_in[8];
    float* out = (float*)d_out;

    // ws layout (192 MiB):
    //  [0,64MiB)    xb (bf16 x)  -- dead after gemm1; then state arrays (6 x 4 MiB)
    //  [64,128MiB)  din1 (bf16)  -- becomes mems in-place at scanA
    //  [128,192MiB) din2 (bf16)
    char* w = (char*)d_ws;
    unsigned short* xb   = (unsigned short*)(w);
    unsigned short* din1 = (unsigned short*)(w + (size_t)64 * 1024 * 1024);
    unsigned short* din2 = (unsigned short*)(w + (size_t)128 * 1024 * 1024);
    float* Sd1 = (float*)w;                     // each array: 32*64*512 f32 = 4 MiB
    float* Sd2 = Sd1 + (1u << 20);
    float* Sm  = Sd1 + (2u << 20);
    float* D1  = Sd1 + (3u << 20);
    float* D2  = Sd1 + (4u << 20);
    float* DM  = Sd1 + (5u << 20);

    cast_kernel<<<dim3(16384), 256, 0, stream>>>(x, (unsigned int*)xb);
    gemm1_kernel<<<dim3(4, 512, 2), 256, 0, stream>>>(xb, w1, w2, din1, din2);
    scanA_kernel<<<dim3(B_ * NC), 256, 0, stream>>>((unsigned int*)din1,
                                                    (const unsigned int*)din2,
                                                    b1, tau1, b2, tau2, Sd1, Sd2, Sm);
    scanB_kernel<<<dim3(128), 128, 0, stream>>>(Sd1, Sd2, Sm, tau1, tau2, D1, D2, DM);
    scanC_kernel<<<dim3(B_ * (NC - 1)), 256, 0, stream>>>((unsigned int*)din1,
                                                          tau1, tau2, D1, D2, DM);
    gemm2_kernel<<<dim3(512), 256, 0, stream>>>(din1, wo, bo, out);
}

// Round 3
// 364.766 us; speedup vs baseline: 1.4533x; 1.0040x over previous
//
#include <hip/hip_runtime.h>

// B=64 T=1024 D=512 H=512 O=128 HALF=256 ALPHA_M=0.8
// Pipeline:
//   gtab   : fix-up coefficient tables G1/G2 [32][512] f32
//   cast   : x fp32 -> xb bf16
//   gemm1f : both-branch MFMA GEMM + in-LDS local chunk scan -> mems (bf16) + chunk states
//   scanB  : sequential chunk-state combine -> D1/D2/DM prefix states (c=0 zeroed)
//   gemm2f : fix-up applied during VALU A-staging + MFMA + bias + sigmoid -> out fp32

#define B_    64
#define T_    1024
#define D_    512
#define H_    512
#define O_    128
#define HALF_ 256
#define CLEN  32
#define NC    32

typedef __attribute__((ext_vector_type(4))) float        f32x4;
typedef __attribute__((ext_vector_type(2))) float        f32x2;
typedef __attribute__((ext_vector_type(8))) short        s16x8;
typedef __attribute__((ext_vector_type(4))) unsigned int u32x4;

__device__ __forceinline__ unsigned short f2bf(float f) {
    unsigned u = __float_as_uint(f);
    return (unsigned short)((u + 0x7fffu + ((u >> 16) & 1u)) >> 16);  // RNE
}
__device__ __forceinline__ unsigned packbf(float a, float b) {
    return (unsigned)f2bf(a) | ((unsigned)f2bf(b) << 16);
}
__device__ __forceinline__ float bflo(unsigned u) { return __uint_as_float(u << 16); }
__device__ __forceinline__ float bfhi(unsigned u) { return __uint_as_float(u & 0xffff0000u); }
__device__ __forceinline__ float sigf(float x) { return 1.f / (1.f + __expf(-x)); }
__device__ __forceinline__ float guard(float dn) {
    if (fabsf(dn) < 1e-6f) dn = (dn < 0.f ? -1e-6f : 1e-6f);
    return dn;
}
__device__ __forceinline__ float pw32(float a) {  // a^32
    float t = a * a; t *= t; t *= t; t *= t; t *= t; return t;
}

typedef const __attribute__((address_space(1))) unsigned int gu32;
typedef __attribute__((address_space(3))) unsigned int      lu32;
__device__ __forceinline__ void gl_lds16(const void* g, void* l) {
    __builtin_amdgcn_global_load_lds((gu32*)g, (lu32*)l, 16, 0, 0);
}

// ---------------- gtab: G1[k][h] = c1(h)*(0.8^{k+1} - a1(h)^{k+1}), same G2 --------------
__global__ __launch_bounds__(256) void gtab_kernel(
    const float* __restrict__ tau1, const float* __restrict__ tau2,
    float* __restrict__ G1, float* __restrict__ G2)
{
    const int h = blockIdx.x * 256 + threadIdx.x;   // 0..511
    const float a1 = sigf(tau1[h]), a2 = sigf(tau2[h]);
    const float c1 = 0.2f * a1 / guard(0.8f - a1);
    const float c2 = 0.2f * a2 / guard(0.8f - a2);
    float pm = 1.f, p1 = 1.f, p2 = 1.f;
    for (int k = 0; k < CLEN; ++k) {
        pm *= 0.8f; p1 *= a1; p2 *= a2;
        G1[k * H_ + h] = c1 * (pm - p1);
        G2[k * H_ + h] = c2 * (pm - p2);
    }
}

// ---------------- cast: x fp32 -> xb bf16 (packed) ---------------------------------------
__global__ __launch_bounds__(256) void cast_kernel(const float* __restrict__ x,
                                                   unsigned int* __restrict__ xb) {
    size_t i = ((size_t)blockIdx.x * 256 + threadIdx.x) * 8;
    f32x4 a = *(const f32x4*)(x + i);
    f32x4 b = *(const f32x4*)(x + i + 4);
    u32x4 p;
    p.x = packbf(a.x, a.y); p.y = packbf(a.z, a.w);
    p.z = packbf(b.x, b.y); p.w = packbf(b.z, b.w);
    *(u32x4*)(xb + i / 2) = p;
}

// ---------------- gemm1f: both branches MFMA + in-LDS local scan -------------------------
__global__ __launch_bounds__(256, 2) void gemm1f_kernel(
    const unsigned short* __restrict__ xb, const float* __restrict__ w1,
    const float* __restrict__ w2,
    const float* __restrict__ b1, const float* __restrict__ tau1,
    const float* __restrict__ b2, const float* __restrict__ tau2,
    unsigned int* __restrict__ mems,
    float* __restrict__ Sd1, float* __restrict__ Sd2, float* __restrict__ Sm)
{
    __shared__ short smem[32768];          // 64 KB
    short* As  = smem;                     // 16 KB  (staging A)
    short* Bs  = smem + 8192;              // 16 KB  (staging B)
    short* d1L = smem + 16384;             // 32 KB  (din1 tile 128x128 bf16)
    short* d2L = smem;                     // 32 KB  (din2 tile; reuses As+Bs)

    const int nt = blockIdx.x;             // 0..3   h-tile
    const int mt = blockIdx.y;             // 0..511 m-tile
    const int b  = mt >> 3;
    const int t0 = (mt & 7) << 7;

    const int tid = threadIdx.x, l = tid & 63, wv = tid >> 6;
    const int ln = l & 15, qd = l >> 4;
    const int wm = (wv & 1) << 6, wn = (wv >> 1) << 6;

    for (int br = 0; br < 2; ++br) {
        const float* w = br ? w2 : w1;
        const unsigned short* abase = xb + (size_t)(mt * 128) * D_ + br * HALF_;
        const float* wbase = w + (size_t)(nt * 128) * HALF_;

        f32x4 acc[4][4] = {};

        for (int kt = 0; kt < HALF_; kt += 64) {
            #pragma unroll
            for (int i = 0; i < 4; ++i) {
                int ch = wv * 4 + i;
                int r  = ch * 8 + (l >> 3);
                int kbl = (l & 7) ^ (r & 7);
                gl_lds16(abase + (size_t)r * D_ + kt + kbl * 8, &As[ch * 512 + l * 8]);
            }
            #pragma unroll
            for (int i = 0; i < 4; ++i) {
                int gi = i * 256 + tid;
                int r = gi >> 3, kbp = gi & 7, kbl = kbp ^ (r & 7);
                const float* src = wbase + (size_t)r * HALF_ + kt + kbl * 8;
                f32x4 b0 = *(const f32x4*)src;
                f32x4 b1v = *(const f32x4*)(src + 4);
                u32x4 pb;
                pb.x = packbf(b0.x, b0.y); pb.y = packbf(b0.z, b0.w);
                pb.z = packbf(b1v.x, b1v.y); pb.w = packbf(b1v.z, b1v.w);
                *(u32x4*)&Bs[r * 64 + kbp * 8] = pb;
            }
            __syncthreads();
            #pragma unroll
            for (int ks = 0; ks < 64; ks += 32) {
                s16x8 af[4], bfv[4];
                #pragma unroll
                for (int i = 0; i < 4; ++i) {
                    int r = wm + i * 16 + ln;
                    int kbp = ((ks >> 3) + qd) ^ (r & 7);
                    af[i] = *(const s16x8*)&As[r * 64 + kbp * 8];
                }
                #pragma unroll
                for (int j = 0; j < 4; ++j) {
                    int r = wn + j * 16 + ln;
                    int kbp = ((ks >> 3) + qd) ^ (r & 7);
                    bfv[j] = *(const s16x8*)&Bs[r * 64 + kbp * 8];
                }
                #pragma unroll
                for (int i = 0; i < 4; ++i)
                    #pragma unroll
                    for (int j = 0; j < 4; ++j)
                        acc[i][j] = __builtin_amdgcn_mfma_f32_16x16x32_bf16(
                            af[i], bfv[j], acc[i][j], 0, 0, 0);
            }
            __syncthreads();
        }

        // dump din tile to LDS: [t_local][h_local], bf16
        short* dL = br ? d2L : d1L;
        #pragma unroll
        for (int i = 0; i < 4; ++i)
            #pragma unroll
            for (int j = 0; j < 4; ++j)
                #pragma unroll
                for (int r = 0; r < 4; ++r)
                    dL[(wm + i * 16 + qd * 4 + r) * 128 + wn + j * 16 + ln] =
                        (short)f2bf(acc[i][j][r]);
    }
    __syncthreads();

    // local chunk scans from LDS: thread = (chunk cl = tid>>6, h-pair h2l = tid&63)
    const int cl  = tid >> 6;
    const int h2l = tid & 63;
    const int hl0 = h2l << 1;
    const int hg0 = nt * 128 + hl0;
    const int cg  = ((mt & 7) << 2) + cl;

    const float a1a = sigf(tau1[hg0]), a1b = sigf(tau1[hg0 + 1]);
    const float a2a = sigf(tau2[hg0]), a2b = sigf(tau2[hg0 + 1]);
    const float o1a = 1.f - a1a, o1b = 1.f - a1b;
    const float o2a = 1.f - a2a, o2b = 1.f - a2b;
    const float bb1a = b1[hg0], bb1b = b1[hg0 + 1];
    const float bb2a = b2[hg0], bb2b = b2[hg0 + 1];

    float d1a = 0.f, d1b = 0.f, d2a = 0.f, d2b = 0.f, ma = 0.f, mb = 0.f;
    const size_t mrow = (size_t)(b * T_ + t0 + cl * CLEN) * (H_ / 2) + nt * 64 + h2l;

    #pragma unroll 8
    for (int k = 0; k < CLEN; ++k) {
        unsigned u1 = *(const unsigned*)&d1L[(cl * CLEN + k) * 128 + hl0];
        unsigned u2 = *(const unsigned*)&d2L[(cl * CLEN + k) * 128 + hl0];
        float i1a = bflo(u1) + bb1a, i1b = bfhi(u1) + bb1b;
        float i2a = bflo(u2) + bb2a, i2b = bfhi(u2) + bb2b;
        d1a = a1a * d1a + o1a * i1a;  d1b = a1b * d1b + o1b * i1b;
        d2a = a2a * d2a + o2a * i2a;  d2b = a2b * d2b + o2b * i2b;
        ma = 0.8f * ma + 0.2f * (d1a + d2a);
        mb = 0.8f * mb + 0.2f * (d1b + d2b);
        mems[mrow + (size_t)k * (H_ / 2)] = packbf(ma, mb);
    }

    const size_t si = (size_t)(cg * B_ + b) * H_ + hg0;
    f32x2 v;
    v.x = d1a; v.y = d1b; *(f32x2*)&Sd1[si] = v;
    v.x = d2a; v.y = d2b; *(f32x2*)&Sd2[si] = v;
    v.x = ma;  v.y = mb;  *(f32x2*)&Sm[si]  = v;
}

// ---------------- scanB: sequential chunk-state combine (writes c=0 zeros) ---------------
__global__ __launch_bounds__(128) void scanB_kernel(
    const float* __restrict__ Sd1, const float* __restrict__ Sd2,
    const float* __restrict__ Sm,
    const float* __restrict__ tau1, const float* __restrict__ tau2,
    float* __restrict__ D1, float* __restrict__ D2, float* __restrict__ DM)
{
    const int g = blockIdx.x * 128 + threadIdx.x;  // 0..16383
    const int h2 = g & 255, b = g >> 8, h0 = h2 << 1;

    const float a1a = sigf(tau1[h0]), a1b = sigf(tau1[h0 + 1]);
    const float a2a = sigf(tau2[h0]), a2b = sigf(tau2[h0 + 1]);
    const float amL = pw32(0.8f);
    const float a1La = pw32(a1a), a1Lb = pw32(a1b);
    const float a2La = pw32(a2a), a2Lb = pw32(a2b);

    const float c1a = 0.2f * a1a / guard(0.8f - a1a);
    const float c1b = 0.2f * a1b / guard(0.8f - a1b);
    const float c2a = 0.2f * a2a / guard(0.8f - a2a);
    const float c2b = 0.2f * a2b / guard(0.8f - a2b);

    const float g1La = c1a * (amL - a1La), g1Lb = c1b * (amL - a1Lb);
    const float g2La = c2a * (amL - a2La), g2Lb = c2b * (amL - a2Lb);

    float D1a = 0.f, D1b = 0.f, D2a = 0.f, D2b = 0.f, Ma = 0.f, Mb = 0.f;
    for (int c = 0; c < NC; ++c) {
        const size_t si = (size_t)(c * B_ + b) * H_ + h0;
        f32x2 v;
        v.x = D1a; v.y = D1b; *(f32x2*)&D1[si] = v;
        v.x = D2a; v.y = D2b; *(f32x2*)&D2[si] = v;
        v.x = Ma;  v.y = Mb;  *(f32x2*)&DM[si] = v;
        f32x2 s1 = *(const f32x2*)&Sd1[si];
        f32x2 s2 = *(const f32x2*)&Sd2[si];
        f32x2 sm = *(const f32x2*)&Sm[si];
        float nMa = amL * Ma + D1a * g1La + D2a * g2La + sm.x;
        float nMb = amL * Mb + D1b * g1Lb + D2b * g2Lb + sm.y;
        D1a = a1La * D1a + s1.x;  D1b = a1Lb * D1b + s1.y;
        D2a = a2La * D2a + s2.x;  D2b = a2Lb * D2b + s2.y;
        Ma = nMa;  Mb = nMb;
    }
}

// ---------------- gemm2f: fix-up in A-staging + MFMA + bias + sigmoid --------------------
__global__ __launch_bounds__(256, 2) void gemm2f_kernel(
    const unsigned short* __restrict__ mems, const float* __restrict__ wo,
    const float* __restrict__ bo,
    const float* __restrict__ G1, const float* __restrict__ G2,
    const float* __restrict__ D1, const float* __restrict__ D2,
    const float* __restrict__ DM, float* __restrict__ out)
{
    __shared__ short As[128 * 64];
    __shared__ short Bs[128 * 64];
    __shared__ float PMl[CLEN];

    const int mt = blockIdx.x;
    const int b = mt >> 3, c0 = (mt & 7) << 2;
    const int tid = threadIdx.x, l = tid & 63, wv = tid >> 6;
    const int ln = l & 15, qd = l >> 4;
    const int wm = (wv & 1) << 6, wn = (wv >> 1) << 6;

    if (tid < CLEN) {
        float pm = 1.f;
        for (int k = 0; k <= tid; ++k) pm *= 0.8f;
        PMl[tid] = pm;                       // 0.8^{k+1}
    }
    __syncthreads();

    f32x4 acc[4][4] = {};
    const unsigned short* abase = mems + (size_t)(mt * 128) * H_;

    for (int kt = 0; kt < H_; kt += 64) {
        // A staging with fix-up (VALU)
        #pragma unroll
        for (int i = 0; i < 4; ++i) {
            int gi = i * 256 + tid;
            int r = gi >> 3, kbp = gi & 7, kbl = kbp ^ (r & 7);
            int h0 = kt + kbl * 8;
            int k = r & 31, c = c0 + (r >> 5);
            size_t dbase = (size_t)(c * B_ + b) * H_ + h0;
            f32x4 d1a = *(const f32x4*)&D1[dbase], d1b = *(const f32x4*)&D1[dbase + 4];
            f32x4 d2a = *(const f32x4*)&D2[dbase], d2b = *(const f32x4*)&D2[dbase + 4];
            f32x4 dma = *(const f32x4*)&DM[dbase], dmb = *(const f32x4*)&DM[dbase + 4];
            f32x4 g1a = *(const f32x4*)&G1[k * H_ + h0], g1b = *(const f32x4*)&G1[k * H_ + h0 + 4];
            f32x4 g2a = *(const f32x4*)&G2[k * H_ + h0], g2b = *(const f32x4*)&G2[k * H_ + h0 + 4];
            float pm = PMl[k];
            u32x4 mv = *(const u32x4*)(abase + (size_t)r * H_ + h0);
            float v0 = bflo(mv.x) + d1a.x * g1a.x + d2a.x * g2a.x + dma.x * pm;
            float v1 = bfhi(mv.x) + d1a.y * g1a.y + d2a.y * g2a.y + dma.y * pm;
            float v2 = bflo(mv.y) + d1a.z * g1a.z + d2a.z * g2a.z + dma.z * pm;
            float v3 = bfhi(mv.y) + d1a.w * g1a.w + d2a.w * g2a.w + dma.w * pm;
            float v4 = bflo(mv.z) + d1b.x * g1b.x + d2b.x * g2b.x + dmb.x * pm;
            float v5 = bfhi(mv.z) + d1b.y * g1b.y + d2b.y * g2b.y + dmb.y * pm;
            float v6 = bflo(mv.w) + d1b.z * g1b.z + d2b.z * g2b.z + dmb.z * pm;
            float v7 = bfhi(mv.w) + d1b.w * g1b.w + d2b.w * g2b.w + dmb.w * pm;
            u32x4 p;
            p.x = packbf(v0, v1); p.y = packbf(v2, v3);
            p.z = packbf(v4, v5); p.w = packbf(v6, v7);
            *(u32x4*)&As[r * 64 + kbp * 8] = p;
        }
        // B staging: wo fp32 -> bf16
        #pragma unroll
        for (int i = 0; i < 4; ++i) {
            int gi = i * 256 + tid;
            int r = gi >> 3, kbp = gi & 7, kbl = kbp ^ (r & 7);
            const float* src = wo + (size_t)r * H_ + kt + kbl * 8;
            f32x4 b0 = *(const f32x4*)src;
            f32x4 b1v = *(const f32x4*)(src + 4);
            u32x4 pb;
            pb.x = packbf(b0.x, b0.y); pb.y = packbf(b0.z, b0.w);
            pb.z = packbf(b1v.x, b1v.y); pb.w = packbf(b1v.z, b1v.w);
            *(u32x4*)&Bs[r * 64 + kbp * 8] = pb;
        }
        __syncthreads();
        #pragma unroll
        for (int ks = 0; ks < 64; ks += 32) {
            s16x8 af[4], bfv[4];
            #pragma unroll
            for (int i = 0; i < 4; ++i) {
                int r = wm + i * 16 + ln;
                int kbp = ((ks >> 3) + qd) ^ (r & 7);
                af[i] = *(const s16x8*)&As[r * 64 + kbp * 8];
            }
            #pragma unroll
            for (int j = 0; j < 4; ++j) {
                int r = wn + j * 16 + ln;
                int kbp = ((ks >> 3) + qd) ^ (r & 7);
                bfv[j] = *(const s16x8*)&Bs[r * 64 + kbp * 8];
            }
            #pragma unroll
            for (int i = 0; i < 4; ++i)
                #pragma unroll
                for (int j = 0; j < 4; ++j)
                    acc[i][j] = __builtin_amdgcn_mfma_f32_16x16x32_bf16(
                        af[i], bfv[j], acc[i][j], 0, 0, 0);
        }
        __syncthreads();
    }

    float bov[4];
    #pragma unroll
    for (int j = 0; j < 4; ++j) bov[j] = bo[wn + j * 16 + ln];

    float* orow = out + (size_t)(mt * 128 + wm + qd * 4) * O_ + wn + ln;
    #pragma unroll
    for (int i = 0; i < 4; ++i)
        #pragma unroll
        for (int j = 0; j < 4; ++j)
            #pragma unroll
            for (int r = 0; r < 4; ++r) {
                float v = acc[i][j][r] + bov[j];
                orow[(size_t)(i * 16 + r) * O_ + j * 16] = 1.f / (1.f + __expf(-v));
            }
}

extern "C" void kernel_launch(void* const* d_in, const int* in_sizes, int n_in,
                              void* d_out, int out_size, void* d_ws, size_t ws_size,
                              hipStream_t stream) {
    const float* x    = (const float*)d_in[0];
    const float* w1   = (const float*)d_in[1];
    const float* b1   = (const float*)d_in[2];
    const float* tau1 = (const float*)d_in[3];
    const float* w2   = (const float*)d_in[4];
    const float* b2   = (const float*)d_in[5];
    const float* tau2 = (const float*)d_in[6];
    const float* wo   = (const float*)d_in[7];
    const float* bo   = (const float*)d_in[8];
    float* out = (float*)d_out;

    // ws layout:
    //  [0,64Mi)   xb bf16
    //  [64,128Mi) mems bf16
    //  [128Mi..)  Sd1,Sd2,Sm,D1,D2,DM (1M f32 each = 24 MiB), G1,G2 (64 KB each)
    char* w = (char*)d_ws;
    unsigned short* xb   = (unsigned short*)(w);
    unsigned int*   mems = (unsigned int*)(w + (size_t)64 * 1024 * 1024);
    float* Sd1 = (float*)(w + (size_t)128 * 1024 * 1024);
    float* Sd2 = Sd1 + (1u << 20);
    float* Sm  = Sd1 + (2u << 20);
    float* D1  = Sd1 + (3u << 20);
    float* D2  = Sd1 + (4u << 20);
    float* DM  = Sd1 + (5u << 20);
    float* G1  = Sd1 + (6u << 20);
    float* G2  = G1 + CLEN * H_;

    gtab_kernel<<<dim3(2), 256, 0, stream>>>(tau1, tau2, G1, G2);
    cast_kernel<<<dim3(16384), 256, 0, stream>>>(x, (unsigned int*)xb);
    gemm1f_kernel<<<dim3(4, 512), 256, 0, stream>>>(xb, w1, w2, b1, tau1, b2, tau2,
                                                    mems, Sd1, Sd2, Sm);
    scanB_kernel<<<dim3(128), 128, 0, stream>>>(Sd1, Sd2, Sm, tau1, tau2, D1, D2, DM);
    gemm2f_kernel<<<dim3(512), 256, 0, stream>>>((const unsigned short*)mems, wo, bo,
                                                 G1, G2, D1, D2, DM, out);
}